// Round 14
// baseline (119.928 us; speedup 1.0000x reference)
//
#include <hip/hip_runtime.h>
#include <hip/hip_bf16.h>
#include <math.h>

#define N_TOK 5000
#define EMB_D 256
#define W_DIM 100
#define TPAD 5120
#define QPAD 5056
#define NKT  157
#define NKT_PAD 160
#define NSPLIT 8
#define TILES_PS 20
#define NB_EMBED (3 * NKT)       // 471 embed blocks (Q | K | V slices)
#define NB_MASK  1250            // mask blocks: 8 waves x 1 half-row each

typedef __attribute__((ext_vector_type(8)))  short short8_t;
typedef __attribute__((ext_vector_type(16))) float f32x16;
typedef __attribute__((ext_vector_type(2)))  unsigned uint2v;

__device__ __forceinline__ unsigned f2bf(float x) {
    union { float f; unsigned u; } c; c.f = x;
    return (c.u + 0x8000u) >> 16;
}
__device__ __forceinline__ unsigned pack2bf(float lo, float hi) {
    __hip_bfloat162 h2 = __float22bfloat162_rn(make_float2(lo, hi));
    union { __hip_bfloat162 h; unsigned u; } c; c.h = h2;
    return c.u;
}
// C rows (crow(r,h) mapping) -> bf16 operand frag for 16-row block cb:
// lane holds rows cb*16 + 8h..8h+7 (contiguous bf16), col = l31.
__device__ __forceinline__ short8_t mkfrag(const f32x16& c, int cb) {
    const int b = 8 * cb;
    unsigned a0 = pack2bf(c[b + 0], c[b + 1]);
    unsigned a1 = pack2bf(c[b + 2], c[b + 3]);
    unsigned b0 = pack2bf(c[b + 4], c[b + 5]);
    unsigned b1 = pack2bf(c[b + 6], c[b + 7]);
    uint2v s02 = __builtin_amdgcn_permlane32_swap(a0, b0, false, false);
    uint2v s13 = __builtin_amdgcn_permlane32_swap(a1, b1, false, false);
    union { unsigned u[4]; short8_t v; } fr;
    fr.u[0] = s02.x; fr.u[1] = s13.x; fr.u[2] = s02.y; fr.u[3] = s13.y;
    return fr.v;
}

// ---------------------------------------------------------------------------
// Kernel 1: convert the 5 weight matrices (256x256 f32) to bf16. grid (64,5).
// Wb layout: [w_in | wq | wk | wv | w_out], each 65536 bf16.
// ---------------------------------------------------------------------------
__global__ __launch_bounds__(256) void wb16_kernel(
    const float* __restrict__ w_in, const float* __restrict__ wq,
    const float* __restrict__ wk, const float* __restrict__ wv,
    const float* __restrict__ w_out, unsigned short* __restrict__ Wb)
{
    const float* srcs[5] = {w_in, wq, wk, wv, w_out};
    const float* s = srcs[blockIdx.y];
    unsigned short* d = Wb + (size_t)blockIdx.y * 65536;
    int i = (blockIdx.x * 256 + threadIdx.x) * 4;
    float4 v = *(const float4*)(s + i);
    uint2 u;
    u.x = pack2bf(v.x, v.y);
    u.y = pack2bf(v.z, v.w);
    *(uint2*)&d[i] = u;
}

// ---------------------------------------------------------------------------
// Kernel 2 (FUSED): embed (blocks 0..470: 157 Q-slice, 157 K-slice, 157
// V-slice; 8 waves each, wave w owns GEMM1 ct=w and GEMM2 ot=w) +
// mask pack (blocks 471..1720; 8 waves x 1 half-row).
// Mask: pmT[kt][q] KEEP-bits, bit layout p(k) = 8*(k&3) + (k>>2).
// ---------------------------------------------------------------------------
__global__ __launch_bounds__(512) void embed_mask_kernel(
    const float* __restrict__ x, const float* __restrict__ ctx,
    const float* __restrict__ row_embed, const float* __restrict__ col_embed,
    const unsigned short* __restrict__ Wb,
    const float* __restrict__ b_in, const float* __restrict__ bq,
    const float* __restrict__ bk, const float* __restrict__ bv,
    const void* __restrict__ mask_raw,
    unsigned short* __restrict__ Qb, unsigned short* __restrict__ Kb,
    unsigned short* __restrict__ Vt, unsigned* __restrict__ pmT)
{
    __shared__ __align__(16) short8_t toksh[16][64];
    __shared__ int sflag;

    const int b = blockIdx.x;
    const int t = threadIdx.x;
    const int lane = t & 63;
    const int w = t >> 6;                    // wave 0..7

    if (b >= NB_EMBED) {
        // ---------------- mask-pack path ----------------
        if (t < 64) {
            bool bad = false;
            const unsigned* mw = (const unsigned*)mask_raw;
            #pragma unroll
            for (int i = 0; i < 4; ++i) {
                unsigned wd = mw[t * 4 + i];
                if (wd != 0u && wd != 1u && wd != 0x3F800000u) bad = true;
            }
            unsigned long long bb = __ballot(bad);
            if (t == 0) sflag = (bb != 0ull) ? 1 : 0;
        }
        __syncthreads();

        const int idx  = (b - NB_EMBED) * 8 + w;    // 0..9999
        const int q    = idx >> 1;                  // 0..4999
        const int half = idx & 1;                   // chunks half*10..+9

        if (sflag == 0) {
            // word mask: coalesced ballot transpose, loads hoisted for MLP
            const int* row = (const int*)mask_raw + (size_t)q * N_TOK;
            int4 u[10];
            #pragma unroll
            for (int j = 0; j < 10; ++j) {
                int wb = (half * 10 + j) * 256 + lane * 4;
                int wbc = min(wb, N_TOK - 4);       // clamp in-row
                u[j] = *(const int4*)(row + wbc);
            }
            #pragma unroll
            for (int j = 0; j < 10; ++j) {
                const int c  = half * 10 + j;
                const int wb = c * 256 + lane * 4;
                unsigned long long B0, B1, B2, B3;
                if (c < 19) {
                    B0 = __ballot(u[j].x == 0);
                    B1 = __ballot(u[j].y == 0);
                    B2 = __ballot(u[j].z == 0);
                    B3 = __ballot(u[j].w == 0);
                } else {
                    B0 = __ballot(u[j].x == 0 && wb + 0 < N_TOK);
                    B1 = __ballot(u[j].y == 0 && wb + 1 < N_TOK);
                    B2 = __ballot(u[j].z == 0 && wb + 2 < N_TOK);
                    B3 = __ballot(u[j].w == 0 && wb + 3 < N_TOK);
                }
                if (lane < 8) {
                    unsigned word =  ((unsigned)(B0 >> (8 * lane)) & 0xFFu)
                                  | (((unsigned)(B1 >> (8 * lane)) & 0xFFu) << 8)
                                  | (((unsigned)(B2 >> (8 * lane)) & 0xFFu) << 16)
                                  | (((unsigned)(B3 >> (8 * lane)) & 0xFFu) << 24);
                    pmT[(size_t)(c * 8 + lane) * QPAD + q] = word;
                }
            }
        } else {
            // byte mask fallback (defensively correct; same bit layout)
            const unsigned char* row = (const unsigned char*)mask_raw + (size_t)q * N_TOK;
            for (int kt = half * 80 + lane; kt < half * 80 + 80; kt += 64) {
                unsigned bits = 0;
                int k0 = kt * 32;
                #pragma unroll
                for (int k = 0; k < 32; ++k) {
                    int key = k0 + k;
                    if (key < N_TOK && row[key] == 0)
                        bits |= 1u << (8 * (k & 3) + (k >> 2));
                }
                pmT[(size_t)kt * QPAD + q] = bits;
            }
        }
        return;
    }

    // ---------------- embed path ----------------
    const int l31 = lane & 31, h = lane >> 5;
    const int chb = 8 * h;
    const int which = b / NKT;               // 0: Q(x)  1: K(ctx)  2: V(ctx)
    const int bx = b - which * NKT;
    const int tok0 = bx * 32;
    const int tok  = tok0 + l31;             // <= 5023 < TPAD
    const int tokc = min(tok, N_TOK - 1);    // clamp loads
    const float* img = (which == 0) ? x : ctx;
    const int hh = tokc / W_DIM, ww = tokc - hh * W_DIM;
    const float QSCALE = 0.0625f * 1.4426950408889634f;

    // y frags (all 16, redundantly per wave; lane-identical across waves)
    short8_t yfr[16];
    #pragma unroll
    for (int blk = 0; blk < 16; ++blk) {
        float yv[8];
        #pragma unroll
        for (int j = 0; j < 8; ++j) {
            int ch = blk * 16 + chb + j;
            float pos = (ch < 128) ? col_embed[ww * 128 + ch]
                                   : row_embed[hh * 128 + (ch - 128)];
            yv[j] = img[ch * N_TOK + tokc] + pos;
        }
        union { unsigned u[4]; short8_t v; } pk;
        #pragma unroll
        for (int j = 0; j < 4; ++j) pk.u[j] = pack2bf(yv[2 * j], yv[2 * j + 1]);
        yfr[blk] = pk.v;
    }

    // GEMM1: wave w computes output channel group ct = w (16 MFMA)
    {
        f32x16 c;
        #pragma unroll
        for (int r = 0; r < 16; ++r) c[r] = 0.f;
        #pragma unroll
        for (int blk = 0; blk < 16; ++blk) {
            short8_t wf = *(const short8_t*)(Wb + (size_t)(w * 32 + l31) * 256 + blk * 16 + chb);
            c = __builtin_amdgcn_mfma_f32_32x32x16_bf16(wf, yfr[blk], c, 0, 0, 0);
        }
        #pragma unroll
        for (int m = 0; m < 4; ++m) {
            float4 b4 = *(const float4*)(b_in + w * 32 + 4 * h + 8 * m);
            c[4 * m + 0] += b4.x; c[4 * m + 1] += b4.y;
            c[4 * m + 2] += b4.z; c[4 * m + 3] += b4.w;
        }
        toksh[2 * w + 0][lane] = mkfrag(c, 0);
        toksh[2 * w + 1][lane] = mkfrag(c, 1);
    }
    __syncthreads();
    short8_t tokfr[16];
    #pragma unroll
    for (int blk = 0; blk < 16; ++blk) tokfr[blk] = toksh[blk][lane];

    // GEMM2: wave w owns ot = w
    const unsigned short* W2 = Wb + (which + 1) * 65536;   // wq / wk / wv
    const float* bias2 = (which == 0) ? bq : (which == 1) ? bk : bv;
    const int ot = w;
    f32x16 c;
    #pragma unroll
    for (int r = 0; r < 16; ++r) c[r] = 0.f;
    #pragma unroll
    for (int blk = 0; blk < 16; ++blk) {
        short8_t wf = *(const short8_t*)(W2 + (size_t)(ot * 32 + l31) * 256 + blk * 16 + chb);
        c = __builtin_amdgcn_mfma_f32_32x32x16_bf16(wf, tokfr[blk], c, 0, 0, 0);
    }
    if (which == 0) {
        #pragma unroll
        for (int m = 0; m < 4; ++m) {
            float4 b4 = *(const float4*)(bias2 + ot * 32 + 4 * h + 8 * m);
            c[4 * m + 0] = (c[4 * m + 0] + b4.x) * QSCALE;
            c[4 * m + 1] = (c[4 * m + 1] + b4.y) * QSCALE;
            c[4 * m + 2] = (c[4 * m + 2] + b4.z) * QSCALE;
            c[4 * m + 3] = (c[4 * m + 3] + b4.w) * QSCALE;
        }
    } else {
        #pragma unroll
        for (int m = 0; m < 4; ++m) {
            float4 b4 = *(const float4*)(bias2 + ot * 32 + 4 * h + 8 * m);
            c[4 * m + 0] += b4.x; c[4 * m + 1] += b4.y;
            c[4 * m + 2] += b4.z; c[4 * m + 3] += b4.w;
        }
    }
    if (which == 2) {
        // V^T tile-major: [kt=bx][head][d][k=l31]
        #pragma unroll
        for (int r = 0; r < 16; ++r) {
            int oc = ot * 32 + ((r & 3) + 8 * (r >> 2) + 4 * h);
            int hd = oc >> 5, d = oc & 31;
            Vt[((size_t)bx * 8 + hd) * 1024 + d * 32 + l31] =
                (unsigned short)f2bf(c[r]);
        }
    } else {
        unsigned short* dst = (which == 0) ? Qb : Kb;
        short8_t f0 = mkfrag(c, 0), f1 = mkfrag(c, 1);
        *(short8_t*)(dst + (size_t)ot * TPAD * 32 + (size_t)tok * 32 + chb)      = f0;
        *(short8_t*)(dst + (size_t)ot * TPAD * 32 + (size_t)tok * 32 + 16 + chb) = f1;
    }
}

// ---------------------------------------------------------------------------
// Kernel 3: MFMA flash attention, no-max softmax. Block = 8 waves = 1 qtile x
// 8 ksplits of 20 tiles each (k-space padded to 160 tiles; pads keep=0).
// Wave: 32 queries x 1 head. Swapped QK^T (S^T), O^T = V^T . P^T.
// Tile-major V^T; setprio around MFMA; sbfe keep-bit; persistent zero C-reg;
// 19-iter main loop + epilogue (no per-iter clamp select).
// ---------------------------------------------------------------------------
__global__ __launch_bounds__(512) void attn_mfma_kernel(
    const unsigned short* __restrict__ Qb, const unsigned short* __restrict__ Kb,
    const unsigned short* __restrict__ Vt, const unsigned* __restrict__ pmT,
    unsigned short* __restrict__ AOb)
{
    __shared__ float comb[NSPLIT - 1][17][64];

    const int t    = threadIdx.x;
    const int lane = t & 63;
    const int ks   = t >> 6;                 // 0..7
    const int bid  = blockIdx.x;
    const int head = bid & 7;
    const int q0   = (bid >> 3) * 32;
    const int l31  = lane & 31;
    const int h    = lane >> 5;
    const int grp8 = h * 8;

    const unsigned short* Kh = Kb + (size_t)head * TPAD * 32;
    const unsigned short* Qh = Qb + (size_t)head * TPAD * 32;
    const unsigned short* Vh = Vt + (size_t)head * 1024 + l31 * 32 + grp8;

    short8_t qf0 = *(const short8_t*)(Qh + (size_t)(q0 + l31) * 32 + grp8);
    short8_t qf1 = *(const short8_t*)(Qh + (size_t)(q0 + l31) * 32 + 16 + grp8);

    f32x16 oacc, zacc;
    #pragma unroll
    for (int r = 0; r < 16; ++r) { oacc[r] = 0.f; zacc[r] = 0.f; }
    float lsum = 0.f;

    const int kt0 = ks * TILES_PS;

    short8_t ka0, ka1, va0, va1; unsigned mw;
    {   // preload first tile
        int k0 = kt0 * 32;
        const unsigned short* kp = Kh + (size_t)(k0 + l31) * 32 + grp8;
        ka0 = *(const short8_t*)kp;
        ka1 = *(const short8_t*)(kp + 16);
        va0 = *(const short8_t*)(Vh + (size_t)kt0 * 8192);
        va1 = *(const short8_t*)(Vh + (size_t)kt0 * 8192 + 16);
        mw  = pmT[(size_t)kt0 * QPAD + q0 + l31];
    }

    auto compute = [&](short8_t cka0, short8_t cka1, short8_t cva0,
                       short8_t cva1, unsigned cmw) {
        // S^T = K . Q^T; Q carries scale*log2e
        f32x16 sacc;
        __builtin_amdgcn_s_setprio(1);
        sacc = __builtin_amdgcn_mfma_f32_32x32x16_bf16(cka0, qf0, zacc, 0, 0, 0);
        sacc = __builtin_amdgcn_mfma_f32_32x32x16_bf16(cka1, qf1, sacc, 0, 0, 0);
        __builtin_amdgcn_s_setprio(0);

        const unsigned mwh = cmw >> h;
        float p[16];
        #pragma unroll
        for (int r = 0; r < 16; ++r) {
            float e = __builtin_amdgcn_exp2f(sacc[r]);
            const int pos = 8 * (r & 3) + 2 * (r >> 2);
            int keep = __builtin_amdgcn_sbfe((int)mwh, pos, 1);  // 0 / -1
            p[r] = __int_as_float(__float_as_int(e) & keep);
        }
        {
            float s0 = (p[0] + p[1]) + (p[2] + p[3]);
            float s1 = (p[4] + p[5]) + (p[6] + p[7]);
            float s2 = (p[8] + p[9]) + (p[10] + p[11]);
            float s3 = (p[12] + p[13]) + (p[14] + p[15]);
            lsum += (s0 + s1) + (s2 + s3);
        }

        __builtin_amdgcn_s_setprio(1);
        #pragma unroll
        for (int c = 0; c < 2; ++c) {
            const int b = 8 * c;
            unsigned a0 = pack2bf(p[b + 0], p[b + 1]);
            unsigned b0 = pack2bf(p[b + 4], p[b + 5]);
            unsigned a1 = pack2bf(p[b + 2], p[b + 3]);
            unsigned b1 = pack2bf(p[b + 6], p[b + 7]);
            uint2v s02 = __builtin_amdgcn_permlane32_swap(a0, b0, false, false);
            uint2v s13 = __builtin_amdgcn_permlane32_swap(a1, b1, false, false);
            union { unsigned u[4]; short8_t v; } fr;
            fr.u[0] = s02.x; fr.u[1] = s13.x; fr.u[2] = s02.y; fr.u[3] = s13.y;
            oacc = __builtin_amdgcn_mfma_f32_32x32x16_bf16(c ? cva1 : cva0, fr.v, oacc, 0, 0, 0);
        }
        __builtin_amdgcn_s_setprio(0);
    };

    #pragma unroll 2
    for (int it = 0; it < TILES_PS - 1; ++it) {
        // unconditional prefetch of tile it+1
        int ktn = kt0 + it + 1;
        int k0n = ktn * 32;
        const unsigned short* kpn = Kh + (size_t)(k0n + l31) * 32 + grp8;
        short8_t nka0 = *(const short8_t*)kpn;
        short8_t nka1 = *(const short8_t*)(kpn + 16);
        const unsigned short* vpn = Vh + (size_t)ktn * 8192;
        short8_t nva0 = *(const short8_t*)vpn;
        short8_t nva1 = *(const short8_t*)(vpn + 16);
        unsigned nmw  = pmT[(size_t)ktn * QPAD + q0 + l31];

        compute(ka0, ka1, va0, va1, mw);

        ka0 = nka0; ka1 = nka1; va0 = nva0; va1 = nva1; mw = nmw;
    }
    compute(ka0, ka1, va0, va1, mw);   // epilogue: last tile, no prefetch

    float lfull = lsum + __shfl_xor(lsum, 32);

    if (ks) {
        comb[ks - 1][0][lane] = lfull;
        #pragma unroll
        for (int r = 0; r < 16; ++r) comb[ks - 1][1 + r][lane] = oacc[r];
    }
    __syncthreads();
    if (ks == 0) {
        float den = lfull;
        #pragma unroll
        for (int s = 0; s < NSPLIT - 1; ++s) den += comb[s][0][lane];
        float inv = 1.f / den;
        f32x16 oc2;
        #pragma unroll
        for (int r = 0; r < 16; ++r) {
            float o = oacc[r];
            #pragma unroll
            for (int s = 0; s < NSPLIT - 1; ++s) o += comb[s][1 + r][lane];
            oc2[r] = o * inv;
        }
        short8_t f0 = mkfrag(oc2, 0), f1 = mkfrag(oc2, 1);
        int q = q0 + l31;
        if (q < N_TOK) {
            *(short8_t*)(AOb + (size_t)q * EMB_D + head * 32 + grp8)      = f0;
            *(short8_t*)(AOb + (size_t)q * EMB_D + head * 32 + 16 + grp8) = f1;
        }
    }
}

// ---------------------------------------------------------------------------
// Kernel 4: MFMA output projection. grid (157, 8): blockIdx.y = ot (32 output
// channels). 1 wave/block, 16 MFMA. C-layout == channel-major output.
// ---------------------------------------------------------------------------
__global__ __launch_bounds__(64) void proj_out_kernel(
    const unsigned short* __restrict__ AOb, const unsigned short* __restrict__ Wob,
    const float* __restrict__ b_out, float* __restrict__ out)
{
    const int lane = threadIdx.x;
    const int l31 = lane & 31, h = lane >> 5;
    const int chb = 8 * h;
    const int tok0 = blockIdx.x * 32;
    const int tok  = tok0 + l31;
    const bool vld = tok < N_TOK;
    const int ot = blockIdx.y;

    short8_t afr[16];
    #pragma unroll
    for (int blk = 0; blk < 16; ++blk)
        afr[blk] = *(const short8_t*)(AOb + (size_t)tok * EMB_D + blk * 16 + chb);

    f32x16 c;
    #pragma unroll
    for (int r = 0; r < 16; ++r) c[r] = 0.f;
    #pragma unroll
    for (int blk = 0; blk < 16; ++blk) {
        short8_t wf = *(const short8_t*)(Wob + (size_t)(ot * 32 + l31) * 256 + blk * 16 + chb);
        c = __builtin_amdgcn_mfma_f32_32x32x16_bf16(wf, afr[blk], c, 0, 0, 0);
    }
    #pragma unroll
    for (int m = 0; m < 4; ++m) {
        float4 b4 = *(const float4*)(b_out + ot * 32 + 4 * h + 8 * m);
        if (vld) {
            int row = ot * 32 + 4 * h + 8 * m;
            out[(size_t)(row + 0) * N_TOK + tok] = c[4 * m + 0] + b4.x;
            out[(size_t)(row + 1) * N_TOK + tok] = c[4 * m + 1] + b4.y;
            out[(size_t)(row + 2) * N_TOK + tok] = c[4 * m + 2] + b4.z;
            out[(size_t)(row + 3) * N_TOK + tok] = c[4 * m + 3] + b4.w;
        }
    }
}

// ---------------------------------------------------------------------------
extern "C" void kernel_launch(void* const* d_in, const int* in_sizes, int n_in,
                              void* d_out, int out_size, void* d_ws, size_t ws_size,
                              hipStream_t stream) {
    const float* x         = (const float*)d_in[0];
    const float* ctx       = (const float*)d_in[1];
    const void*  mask      = (const void*) d_in[2];
    const float* row_embed = (const float*)d_in[3];
    const float* col_embed = (const float*)d_in[4];
    const float* w_in      = (const float*)d_in[5];
    const float* b_in      = (const float*)d_in[6];
    const float* wq        = (const float*)d_in[7];
    const float* bq        = (const float*)d_in[8];
    const float* wk        = (const float*)d_in[9];
    const float* bk        = (const float*)d_in[10];
    const float* wv        = (const float*)d_in[11];
    const float* bv        = (const float*)d_in[12];
    const float* w_out     = (const float*)d_in[13];
    const float* b_out     = (const float*)d_in[14];
    float* out = (float*)d_out;

    char* ws = (char*)d_ws;
    unsigned short* Qb  = (unsigned short*)(ws);                    // 2,621,440 B
    unsigned short* Kb  = (unsigned short*)(ws + 2621440);          // 2,621,440 B
    unsigned short* Vt  = (unsigned short*)(ws + 5242880);          // 2,621,440 B
    unsigned*       pmT = (unsigned*)      (ws + 7864320);          // 3,235,840 B
    unsigned short* AOb = (unsigned short*)(ws + 11100160);         // 2,560,000 B
    unsigned short* Wb  = (unsigned short*)(ws + 13660160);         //   655,360 B

    // zero the 3 V^T padding tiles (kt 157..159; tile-major -> one run)
    hipMemsetAsync(Vt + (size_t)NKT * 8 * 1024, 0,
                   (size_t)(NKT_PAD - NKT) * 8 * 1024 * 2, stream);
    wb16_kernel<<<dim3(64, 5), 256, 0, stream>>>(w_in, wq, wk, wv, w_out, Wb);
    embed_mask_kernel<<<dim3(NB_EMBED + NB_MASK), 512, 0, stream>>>(
        x, ctx, row_embed, col_embed, Wb, b_in, bq, bk, bv, mask, Qb, Kb, Vt, pmT);
    attn_mfma_kernel<<<dim3(NKT * 8), 512, 0, stream>>>(Qb, Kb, Vt, pmT, AOb);
    proj_out_kernel<<<dim3(NKT, 8), 64, 0, stream>>>(AOb, Wb + 4 * 65536, b_out, out);
}

// Round 15
// 112.097 us; speedup vs baseline: 1.0699x; 1.0699x over previous
//
#include <hip/hip_runtime.h>
#include <hip/hip_bf16.h>
#include <math.h>

#define N_TOK 5000
#define EMB_D 256
#define W_DIM 100
#define TPAD 5120
#define QPAD 5056
#define NKT  157
#define NKT_PAD 160
#define NSPLIT 8
#define TILES_PS 20
#define NB_EMBED (3 * NKT)       // 471 embed blocks (Q | K | V slices)
#define NB_MASK  1250            // mask blocks: 8 waves x 1 half-row each

typedef __attribute__((ext_vector_type(8)))  short short8_t;
typedef __attribute__((ext_vector_type(16))) float f32x16;
typedef __attribute__((ext_vector_type(2)))  unsigned uint2v;

__device__ __forceinline__ unsigned f2bf(float x) {
    union { float f; unsigned u; } c; c.f = x;
    return (c.u + 0x8000u) >> 16;
}
__device__ __forceinline__ unsigned pack2bf(float lo, float hi) {
    __hip_bfloat162 h2 = __float22bfloat162_rn(make_float2(lo, hi));
    union { __hip_bfloat162 h; unsigned u; } c; c.h = h2;
    return c.u;
}
// C rows (crow(r,h) mapping) -> bf16 operand frag for 16-row block cb:
// lane holds rows cb*16 + 8h..8h+7 (contiguous bf16), col = l31.
__device__ __forceinline__ short8_t mkfrag(const f32x16& c, int cb) {
    const int b = 8 * cb;
    unsigned a0 = pack2bf(c[b + 0], c[b + 1]);
    unsigned a1 = pack2bf(c[b + 2], c[b + 3]);
    unsigned b0 = pack2bf(c[b + 4], c[b + 5]);
    unsigned b1 = pack2bf(c[b + 6], c[b + 7]);
    uint2v s02 = __builtin_amdgcn_permlane32_swap(a0, b0, false, false);
    uint2v s13 = __builtin_amdgcn_permlane32_swap(a1, b1, false, false);
    union { unsigned u[4]; short8_t v; } fr;
    fr.u[0] = s02.x; fr.u[1] = s13.x; fr.u[2] = s02.y; fr.u[3] = s13.y;
    return fr.v;
}

// ---------------------------------------------------------------------------
// Kernel 1: convert the 5 weight matrices (256x256 f32) to bf16. grid (64,5).
// Wb layout: [w_in | wq | wk | wv | w_out], each 65536 bf16.
// ---------------------------------------------------------------------------
__global__ __launch_bounds__(256) void wb16_kernel(
    const float* __restrict__ w_in, const float* __restrict__ wq,
    const float* __restrict__ wk, const float* __restrict__ wv,
    const float* __restrict__ w_out, unsigned short* __restrict__ Wb)
{
    const float* srcs[5] = {w_in, wq, wk, wv, w_out};
    const float* s = srcs[blockIdx.y];
    unsigned short* d = Wb + (size_t)blockIdx.y * 65536;
    int i = (blockIdx.x * 256 + threadIdx.x) * 4;
    float4 v = *(const float4*)(s + i);
    uint2 u;
    u.x = pack2bf(v.x, v.y);
    u.y = pack2bf(v.z, v.w);
    *(uint2*)&d[i] = u;
}

// ---------------------------------------------------------------------------
// Kernel 2 (FUSED): embed (blocks 0..470: 157 Q-slice, 157 K-slice, 157
// V-slice; 8 waves) + mask pack (blocks 471..1720; 8 waves x 1 half-row).
// Embed: COOPERATIVE y-frag build (wave w builds channel-blocks 2w,2w+1 into
// LDS: 16 scalar loads/thread, 8x fewer than redundant build), then GEMM1
// (wave w -> ct=w) with y-frags read from LDS, then GEMM2 (ot=w).
// Mask: pmT[kt][q] KEEP-bits, bit layout p(k) = 8*(k&3) + (k>>2).
// ---------------------------------------------------------------------------
__global__ __launch_bounds__(512) void embed_mask_kernel(
    const float* __restrict__ x, const float* __restrict__ ctx,
    const float* __restrict__ row_embed, const float* __restrict__ col_embed,
    const unsigned short* __restrict__ Wb,
    const float* __restrict__ b_in, const float* __restrict__ bq,
    const float* __restrict__ bk, const float* __restrict__ bv,
    const void* __restrict__ mask_raw,
    unsigned short* __restrict__ Qb, unsigned short* __restrict__ Kb,
    unsigned short* __restrict__ Vt, unsigned* __restrict__ pmT)
{
    __shared__ __align__(16) short8_t ysh[16][64];
    __shared__ __align__(16) short8_t toksh[16][64];
    __shared__ int sflag;

    const int b = blockIdx.x;
    const int t = threadIdx.x;
    const int lane = t & 63;
    const int w = t >> 6;                    // wave 0..7

    if (b >= NB_EMBED) {
        // ---------------- mask-pack path ----------------
        if (t < 64) {
            bool bad = false;
            const unsigned* mw = (const unsigned*)mask_raw;
            #pragma unroll
            for (int i = 0; i < 4; ++i) {
                unsigned wd = mw[t * 4 + i];
                if (wd != 0u && wd != 1u && wd != 0x3F800000u) bad = true;
            }
            unsigned long long bb = __ballot(bad);
            if (t == 0) sflag = (bb != 0ull) ? 1 : 0;
        }
        __syncthreads();

        const int idx  = (b - NB_EMBED) * 8 + w;    // 0..9999
        const int q    = idx >> 1;                  // 0..4999
        const int half = idx & 1;                   // chunks half*10..+9

        if (sflag == 0) {
            // word mask: coalesced ballot transpose, loads hoisted for MLP
            const int* row = (const int*)mask_raw + (size_t)q * N_TOK;
            int4 u[10];
            #pragma unroll
            for (int j = 0; j < 10; ++j) {
                int wb = (half * 10 + j) * 256 + lane * 4;
                int wbc = min(wb, N_TOK - 4);       // clamp in-row
                u[j] = *(const int4*)(row + wbc);
            }
            #pragma unroll
            for (int j = 0; j < 10; ++j) {
                const int c  = half * 10 + j;
                const int wb = c * 256 + lane * 4;
                unsigned long long B0, B1, B2, B3;
                if (c < 19) {
                    B0 = __ballot(u[j].x == 0);
                    B1 = __ballot(u[j].y == 0);
                    B2 = __ballot(u[j].z == 0);
                    B3 = __ballot(u[j].w == 0);
                } else {
                    B0 = __ballot(u[j].x == 0 && wb + 0 < N_TOK);
                    B1 = __ballot(u[j].y == 0 && wb + 1 < N_TOK);
                    B2 = __ballot(u[j].z == 0 && wb + 2 < N_TOK);
                    B3 = __ballot(u[j].w == 0 && wb + 3 < N_TOK);
                }
                if (lane < 8) {
                    unsigned word =  ((unsigned)(B0 >> (8 * lane)) & 0xFFu)
                                  | (((unsigned)(B1 >> (8 * lane)) & 0xFFu) << 8)
                                  | (((unsigned)(B2 >> (8 * lane)) & 0xFFu) << 16)
                                  | (((unsigned)(B3 >> (8 * lane)) & 0xFFu) << 24);
                    pmT[(size_t)(c * 8 + lane) * QPAD + q] = word;
                }
            }
        } else {
            // byte mask fallback (defensively correct; same bit layout)
            const unsigned char* row = (const unsigned char*)mask_raw + (size_t)q * N_TOK;
            for (int kt = half * 80 + lane; kt < half * 80 + 80; kt += 64) {
                unsigned bits = 0;
                int k0 = kt * 32;
                #pragma unroll
                for (int k = 0; k < 32; ++k) {
                    int key = k0 + k;
                    if (key < N_TOK && row[key] == 0)
                        bits |= 1u << (8 * (k & 3) + (k >> 2));
                }
                pmT[(size_t)kt * QPAD + q] = bits;
            }
        }
        return;
    }

    // ---------------- embed path ----------------
    const int l31 = lane & 31, h = lane >> 5;
    const int chb = 8 * h;
    const int which = b / NKT;               // 0: Q(x)  1: K(ctx)  2: V(ctx)
    const int bx = b - which * NKT;
    const int tok0 = bx * 32;
    const int tok  = tok0 + l31;             // <= 5023 < TPAD
    const int tokc = min(tok, N_TOK - 1);    // clamp loads
    const float* img = (which == 0) ? x : ctx;
    const int hh = tokc / W_DIM, ww = tokc - hh * W_DIM;
    const float QSCALE = 0.0625f * 1.4426950408889634f;

    // cooperative y-frag build: wave w builds channel-blocks 2w, 2w+1
    #pragma unroll
    for (int i = 0; i < 2; ++i) {
        const int blk = 2 * w + i;
        float yv[8];
        #pragma unroll
        for (int j = 0; j < 8; ++j) {
            int ch = blk * 16 + chb + j;
            float pos = (ch < 128) ? col_embed[ww * 128 + ch]
                                   : row_embed[hh * 128 + (ch - 128)];
            yv[j] = img[ch * N_TOK + tokc] + pos;
        }
        union { unsigned u[4]; short8_t v; } pk;
        #pragma unroll
        for (int j = 0; j < 4; ++j) pk.u[j] = pack2bf(yv[2 * j], yv[2 * j + 1]);
        ysh[blk][lane] = pk.v;
    }
    __syncthreads();

    // GEMM1: wave w computes output channel group ct = w (16 MFMA),
    // y-frags read from LDS just-in-time.
    {
        f32x16 c;
        #pragma unroll
        for (int r = 0; r < 16; ++r) c[r] = 0.f;
        #pragma unroll
        for (int blk = 0; blk < 16; ++blk) {
            short8_t wf = *(const short8_t*)(Wb + (size_t)(w * 32 + l31) * 256 + blk * 16 + chb);
            c = __builtin_amdgcn_mfma_f32_32x32x16_bf16(wf, ysh[blk][lane], c, 0, 0, 0);
        }
        #pragma unroll
        for (int m = 0; m < 4; ++m) {
            float4 b4 = *(const float4*)(b_in + w * 32 + 4 * h + 8 * m);
            c[4 * m + 0] += b4.x; c[4 * m + 1] += b4.y;
            c[4 * m + 2] += b4.z; c[4 * m + 3] += b4.w;
        }
        __syncthreads();   // all ysh reads done before toksh overwrites nothing
                           // (separate buffers; barrier orders GEMM1 before tokfr reads)
        toksh[2 * w + 0][lane] = mkfrag(c, 0);
        toksh[2 * w + 1][lane] = mkfrag(c, 1);
    }
    __syncthreads();

    // GEMM2: wave w owns ot = w, tok-frags read from LDS just-in-time.
    const unsigned short* W2 = Wb + (which + 1) * 65536;   // wq / wk / wv
    const float* bias2 = (which == 0) ? bq : (which == 1) ? bk : bv;
    const int ot = w;
    f32x16 c;
    #pragma unroll
    for (int r = 0; r < 16; ++r) c[r] = 0.f;
    #pragma unroll
    for (int blk = 0; blk < 16; ++blk) {
        short8_t wf = *(const short8_t*)(W2 + (size_t)(ot * 32 + l31) * 256 + blk * 16 + chb);
        c = __builtin_amdgcn_mfma_f32_32x32x16_bf16(wf, toksh[blk][lane], c, 0, 0, 0);
    }
    if (which == 0) {
        #pragma unroll
        for (int m = 0; m < 4; ++m) {
            float4 b4 = *(const float4*)(bias2 + ot * 32 + 4 * h + 8 * m);
            c[4 * m + 0] = (c[4 * m + 0] + b4.x) * QSCALE;
            c[4 * m + 1] = (c[4 * m + 1] + b4.y) * QSCALE;
            c[4 * m + 2] = (c[4 * m + 2] + b4.z) * QSCALE;
            c[4 * m + 3] = (c[4 * m + 3] + b4.w) * QSCALE;
        }
    } else {
        #pragma unroll
        for (int m = 0; m < 4; ++m) {
            float4 b4 = *(const float4*)(bias2 + ot * 32 + 4 * h + 8 * m);
            c[4 * m + 0] += b4.x; c[4 * m + 1] += b4.y;
            c[4 * m + 2] += b4.z; c[4 * m + 3] += b4.w;
        }
    }
    if (which == 2) {
        // V^T tile-major: [kt=bx][head][d][k=l31]
        #pragma unroll
        for (int r = 0; r < 16; ++r) {
            int oc = ot * 32 + ((r & 3) + 8 * (r >> 2) + 4 * h);
            int hd = oc >> 5, d = oc & 31;
            Vt[((size_t)bx * 8 + hd) * 1024 + d * 32 + l31] =
                (unsigned short)f2bf(c[r]);
        }
    } else {
        unsigned short* dst = (which == 0) ? Qb : Kb;
        short8_t f0 = mkfrag(c, 0), f1 = mkfrag(c, 1);
        *(short8_t*)(dst + (size_t)ot * TPAD * 32 + (size_t)tok * 32 + chb)      = f0;
        *(short8_t*)(dst + (size_t)ot * TPAD * 32 + (size_t)tok * 32 + 16 + chb) = f1;
    }
}

// ---------------------------------------------------------------------------
// Kernel 3: MFMA flash attention, no-max softmax. Block = 8 waves = 1 qtile x
// 8 ksplits of 20 tiles each (k-space padded to 160 tiles; pads keep=0).
// Wave: 32 queries x 1 head. Swapped QK^T (S^T), O^T = V^T . P^T.
// Tile-major V^T; setprio around MFMA; sbfe keep-bit; persistent zero C-reg;
// 19-iter main loop + epilogue.
// ---------------------------------------------------------------------------
__global__ __launch_bounds__(512) void attn_mfma_kernel(
    const unsigned short* __restrict__ Qb, const unsigned short* __restrict__ Kb,
    const unsigned short* __restrict__ Vt, const unsigned* __restrict__ pmT,
    unsigned short* __restrict__ AOb)
{
    __shared__ float comb[NSPLIT - 1][17][64];

    const int t    = threadIdx.x;
    const int lane = t & 63;
    const int ks   = t >> 6;                 // 0..7
    const int bid  = blockIdx.x;
    const int head = bid & 7;
    const int q0   = (bid >> 3) * 32;
    const int l31  = lane & 31;
    const int h    = lane >> 5;
    const int grp8 = h * 8;

    const unsigned short* Kh = Kb + (size_t)head * TPAD * 32;
    const unsigned short* Qh = Qb + (size_t)head * TPAD * 32;
    const unsigned short* Vh = Vt + (size_t)head * 1024 + l31 * 32 + grp8;

    short8_t qf0 = *(const short8_t*)(Qh + (size_t)(q0 + l31) * 32 + grp8);
    short8_t qf1 = *(const short8_t*)(Qh + (size_t)(q0 + l31) * 32 + 16 + grp8);

    f32x16 oacc, zacc;
    #pragma unroll
    for (int r = 0; r < 16; ++r) { oacc[r] = 0.f; zacc[r] = 0.f; }
    float lsum = 0.f;

    const int kt0 = ks * TILES_PS;

    short8_t ka0, ka1, va0, va1; unsigned mw;
    {   // preload first tile
        int k0 = kt0 * 32;
        const unsigned short* kp = Kh + (size_t)(k0 + l31) * 32 + grp8;
        ka0 = *(const short8_t*)kp;
        ka1 = *(const short8_t*)(kp + 16);
        va0 = *(const short8_t*)(Vh + (size_t)kt0 * 8192);
        va1 = *(const short8_t*)(Vh + (size_t)kt0 * 8192 + 16);
        mw  = pmT[(size_t)kt0 * QPAD + q0 + l31];
    }

    auto compute = [&](short8_t cka0, short8_t cka1, short8_t cva0,
                       short8_t cva1, unsigned cmw) {
        // S^T = K . Q^T; Q carries scale*log2e
        f32x16 sacc;
        __builtin_amdgcn_s_setprio(1);
        sacc = __builtin_amdgcn_mfma_f32_32x32x16_bf16(cka0, qf0, zacc, 0, 0, 0);
        sacc = __builtin_amdgcn_mfma_f32_32x32x16_bf16(cka1, qf1, sacc, 0, 0, 0);
        __builtin_amdgcn_s_setprio(0);

        const unsigned mwh = cmw >> h;
        float p[16];
        #pragma unroll
        for (int r = 0; r < 16; ++r) {
            float e = __builtin_amdgcn_exp2f(sacc[r]);
            const int pos = 8 * (r & 3) + 2 * (r >> 2);
            int keep = __builtin_amdgcn_sbfe((int)mwh, pos, 1);  // 0 / -1
            p[r] = __int_as_float(__float_as_int(e) & keep);
        }
        {
            float s0 = (p[0] + p[1]) + (p[2] + p[3]);
            float s1 = (p[4] + p[5]) + (p[6] + p[7]);
            float s2 = (p[8] + p[9]) + (p[10] + p[11]);
            float s3 = (p[12] + p[13]) + (p[14] + p[15]);
            lsum += (s0 + s1) + (s2 + s3);
        }

        __builtin_amdgcn_s_setprio(1);
        #pragma unroll
        for (int c = 0; c < 2; ++c) {
            const int b = 8 * c;
            unsigned a0 = pack2bf(p[b + 0], p[b + 1]);
            unsigned b0 = pack2bf(p[b + 4], p[b + 5]);
            unsigned a1 = pack2bf(p[b + 2], p[b + 3]);
            unsigned b1 = pack2bf(p[b + 6], p[b + 7]);
            uint2v s02 = __builtin_amdgcn_permlane32_swap(a0, b0, false, false);
            uint2v s13 = __builtin_amdgcn_permlane32_swap(a1, b1, false, false);
            union { unsigned u[4]; short8_t v; } fr;
            fr.u[0] = s02.x; fr.u[1] = s13.x; fr.u[2] = s02.y; fr.u[3] = s13.y;
            oacc = __builtin_amdgcn_mfma_f32_32x32x16_bf16(c ? cva1 : cva0, fr.v, oacc, 0, 0, 0);
        }
        __builtin_amdgcn_s_setprio(0);
    };

    #pragma unroll 2
    for (int it = 0; it < TILES_PS - 1; ++it) {
        int ktn = kt0 + it + 1;
        int k0n = ktn * 32;
        const unsigned short* kpn = Kh + (size_t)(k0n + l31) * 32 + grp8;
        short8_t nka0 = *(const short8_t*)kpn;
        short8_t nka1 = *(const short8_t*)(kpn + 16);
        const unsigned short* vpn = Vh + (size_t)ktn * 8192;
        short8_t nva0 = *(const short8_t*)vpn;
        short8_t nva1 = *(const short8_t*)(vpn + 16);
        unsigned nmw  = pmT[(size_t)ktn * QPAD + q0 + l31];

        compute(ka0, ka1, va0, va1, mw);

        ka0 = nka0; ka1 = nka1; va0 = nva0; va1 = nva1; mw = nmw;
    }
    compute(ka0, ka1, va0, va1, mw);   // epilogue: last tile, no prefetch

    float lfull = lsum + __shfl_xor(lsum, 32);

    if (ks) {
        comb[ks - 1][0][lane] = lfull;
        #pragma unroll
        for (int r = 0; r < 16; ++r) comb[ks - 1][1 + r][lane] = oacc[r];
    }
    __syncthreads();
    if (ks == 0) {
        float den = lfull;
        #pragma unroll
        for (int s = 0; s < NSPLIT - 1; ++s) den += comb[s][0][lane];
        float inv = 1.f / den;
        f32x16 oc2;
        #pragma unroll
        for (int r = 0; r < 16; ++r) {
            float o = oacc[r];
            #pragma unroll
            for (int s = 0; s < NSPLIT - 1; ++s) o += comb[s][1 + r][lane];
            oc2[r] = o * inv;
        }
        short8_t f0 = mkfrag(oc2, 0), f1 = mkfrag(oc2, 1);
        int q = q0 + l31;
        if (q < N_TOK) {
            *(short8_t*)(AOb + (size_t)q * EMB_D + head * 32 + grp8)      = f0;
            *(short8_t*)(AOb + (size_t)q * EMB_D + head * 32 + 16 + grp8) = f1;
        }
    }
}

// ---------------------------------------------------------------------------
// Kernel 4: MFMA output projection. grid (157, 8): blockIdx.y = ot (32 output
// channels). 1 wave/block, 16 MFMA. C-layout == channel-major output.
// ---------------------------------------------------------------------------
__global__ __launch_bounds__(64) void proj_out_kernel(
    const unsigned short* __restrict__ AOb, const unsigned short* __restrict__ Wob,
    const float* __restrict__ b_out, float* __restrict__ out)
{
    const int lane = threadIdx.x;
    const int l31 = lane & 31, h = lane >> 5;
    const int chb = 8 * h;
    const int tok0 = blockIdx.x * 32;
    const int tok  = tok0 + l31;
    const bool vld = tok < N_TOK;
    const int ot = blockIdx.y;

    short8_t afr[16];
    #pragma unroll
    for (int blk = 0; blk < 16; ++blk)
        afr[blk] = *(const short8_t*)(AOb + (size_t)tok * EMB_D + blk * 16 + chb);

    f32x16 c;
    #pragma unroll
    for (int r = 0; r < 16; ++r) c[r] = 0.f;
    #pragma unroll
    for (int blk = 0; blk < 16; ++blk) {
        short8_t wf = *(const short8_t*)(Wob + (size_t)(ot * 32 + l31) * 256 + blk * 16 + chb);
        c = __builtin_amdgcn_mfma_f32_32x32x16_bf16(wf, afr[blk], c, 0, 0, 0);
    }
    #pragma unroll
    for (int m = 0; m < 4; ++m) {
        float4 b4 = *(const float4*)(b_out + ot * 32 + 4 * h + 8 * m);
        if (vld) {
            int row = ot * 32 + 4 * h + 8 * m;
            out[(size_t)(row + 0) * N_TOK + tok] = c[4 * m + 0] + b4.x;
            out[(size_t)(row + 1) * N_TOK + tok] = c[4 * m + 1] + b4.y;
            out[(size_t)(row + 2) * N_TOK + tok] = c[4 * m + 2] + b4.z;
            out[(size_t)(row + 3) * N_TOK + tok] = c[4 * m + 3] + b4.w;
        }
    }
}

// ---------------------------------------------------------------------------
extern "C" void kernel_launch(void* const* d_in, const int* in_sizes, int n_in,
                              void* d_out, int out_size, void* d_ws, size_t ws_size,
                              hipStream_t stream) {
    const float* x         = (const float*)d_in[0];
    const float* ctx       = (const float*)d_in[1];
    const void*  mask      = (const void*) d_in[2];
    const float* row_embed = (const float*)d_in[3];
    const float* col_embed = (const float*)d_in[4];
    const float* w_in      = (const float*)d_in[5];
    const float* b_in      = (const float*)d_in[6];
    const float* wq        = (const float*)d_in[7];
    const float* bq        = (const float*)d_in[8];
    const float* wk        = (const float*)d_in[9];
    const float* bk        = (const float*)d_in[10];
    const float* wv        = (const float*)d_in[11];
    const float* bv        = (const float*)d_in[12];
    const float* w_out     = (const float*)d_in[13];
    const float* b_out     = (const float*)d_in[14];
    float* out = (float*)d_out;

    char* ws = (char*)d_ws;
    unsigned short* Qb  = (unsigned short*)(ws);                    // 2,621,440 B
    unsigned short* Kb  = (unsigned short*)(ws + 2621440);          // 2,621,440 B
    unsigned short* Vt  = (unsigned short*)(ws + 5242880);          // 2,621,440 B
    unsigned*       pmT = (unsigned*)      (ws + 7864320);          // 3,235,840 B
    unsigned short* AOb = (unsigned short*)(ws + 11100160);         // 2,560,000 B
    unsigned short* Wb  = (unsigned short*)(ws + 13660160);         //   655,360 B

    // zero the 3 V^T padding tiles (kt 157..159; tile-major -> one run)
    hipMemsetAsync(Vt + (size_t)NKT * 8 * 1024, 0,
                   (size_t)(NKT_PAD - NKT) * 8 * 1024 * 2, stream);
    wb16_kernel<<<dim3(64, 5), 256, 0, stream>>>(w_in, wq, wk, wv, w_out, Wb);
    embed_mask_kernel<<<dim3(NB_EMBED + NB_MASK), 512, 0, stream>>>(
        x, ctx, row_embed, col_embed, Wb, b_in, bq, bk, bv, mask, Qb, Kb, Vt, pmT);
    attn_mfma_kernel<<<dim3(NKT * 8), 512, 0, stream>>>(Qb, Kb, Vt, pmT, AOb);
    proj_out_kernel<<<dim3(NKT, 8), 64, 0, stream>>>(AOb, Wb + 4 * 65536, b_out, out);
}

// Round 16
// 111.685 us; speedup vs baseline: 1.0738x; 1.0037x over previous
//
#include <hip/hip_runtime.h>
#include <hip/hip_bf16.h>
#include <math.h>

#define N_TOK 5000
#define EMB_D 256
#define W_DIM 100
#define TPAD 5120
#define QPAD 5056
#define NKT  157
#define NKT_PAD 160
#define NSPLIT 8
#define TILES_PS 20
#define NB_EMBED (3 * NKT)       // 471 embed blocks (Q | K | V slices)
#define NB_MASK  1250            // mask blocks: 8 waves x 1 half-row each

typedef __attribute__((ext_vector_type(8)))  short short8_t;
typedef __attribute__((ext_vector_type(16))) float f32x16;
typedef __attribute__((ext_vector_type(2)))  unsigned uint2v;

__device__ __forceinline__ unsigned f2bf(float x) {
    union { float f; unsigned u; } c; c.f = x;
    return (c.u + 0x8000u) >> 16;
}
__device__ __forceinline__ unsigned pack2bf(float lo, float hi) {
    __hip_bfloat162 h2 = __float22bfloat162_rn(make_float2(lo, hi));
    union { __hip_bfloat162 h; unsigned u; } c; c.h = h2;
    return c.u;
}
// C rows (crow(r,h) mapping) -> bf16 operand frag for 16-row block cb:
// lane holds rows cb*16 + 8h..8h+7 (contiguous bf16), col = l31.
__device__ __forceinline__ short8_t mkfrag(const f32x16& c, int cb) {
    const int b = 8 * cb;
    unsigned a0 = pack2bf(c[b + 0], c[b + 1]);
    unsigned a1 = pack2bf(c[b + 2], c[b + 3]);
    unsigned b0 = pack2bf(c[b + 4], c[b + 5]);
    unsigned b1 = pack2bf(c[b + 6], c[b + 7]);
    uint2v s02 = __builtin_amdgcn_permlane32_swap(a0, b0, false, false);
    uint2v s13 = __builtin_amdgcn_permlane32_swap(a1, b1, false, false);
    union { unsigned u[4]; short8_t v; } fr;
    fr.u[0] = s02.x; fr.u[1] = s13.x; fr.u[2] = s02.y; fr.u[3] = s13.y;
    return fr.v;
}

// ---------------------------------------------------------------------------
// Kernel 1: convert the 5 weight matrices (256x256 f32) to bf16 (grid.y 0..4)
// + detect mask dtype ONCE (grid.y == 5, block 0): word mask (0/1/1.0f) vs
// packed byte mask. Writes flag to workspace so mask blocks skip detection.
// ---------------------------------------------------------------------------
__global__ __launch_bounds__(256) void wb16_kernel(
    const float* __restrict__ w_in, const float* __restrict__ wq,
    const float* __restrict__ wk, const float* __restrict__ wv,
    const float* __restrict__ w_out, const unsigned* __restrict__ mask,
    unsigned short* __restrict__ Wb, int* __restrict__ mflag)
{
    if (blockIdx.y == 5) {
        if (blockIdx.x == 0 && threadIdx.x < 64) {
            int t = threadIdx.x;
            bool bad = false;
            #pragma unroll
            for (int i = 0; i < 4; ++i) {
                unsigned wd = mask[t * 4 + i];
                if (wd != 0u && wd != 1u && wd != 0x3F800000u) bad = true;
            }
            unsigned long long bb = __ballot(bad);
            if (t == 0) *mflag = (bb != 0ull) ? 1 : 0;
        }
        return;
    }
    const float* srcs[5] = {w_in, wq, wk, wv, w_out};
    const float* s = srcs[blockIdx.y];
    unsigned short* d = Wb + (size_t)blockIdx.y * 65536;
    int i = (blockIdx.x * 256 + threadIdx.x) * 4;
    float4 v = *(const float4*)(s + i);
    uint2 u;
    u.x = pack2bf(v.x, v.y);
    u.y = pack2bf(v.z, v.w);
    *(uint2*)&d[i] = u;
}

// ---------------------------------------------------------------------------
// Kernel 2 (FUSED): embed (blocks 0..470: 157 Q-slice, 157 K-slice, 157
// V-slice; 8 waves) + mask pack (blocks 471..1720; 8 waves x 1 half-row).
// Embed: cooperative y-frag build (wave w builds channel-blocks 2w,2w+1 into
// LDS), GEMM1 (ct=w) from LDS y-frags, GEMM2 (ot=w) from LDS tok-frags.
// Mask: pmT[kt][q] KEEP-bits, bit layout p(k) = 8*(k&3) + (k>>2); dtype flag
// pre-computed (uniform scalar load, no barrier); clamp only on last chunk.
// ---------------------------------------------------------------------------
__global__ __launch_bounds__(512) void embed_mask_kernel(
    const float* __restrict__ x, const float* __restrict__ ctx,
    const float* __restrict__ row_embed, const float* __restrict__ col_embed,
    const unsigned short* __restrict__ Wb,
    const float* __restrict__ b_in, const float* __restrict__ bq,
    const float* __restrict__ bk, const float* __restrict__ bv,
    const void* __restrict__ mask_raw, const int* __restrict__ mflag,
    unsigned short* __restrict__ Qb, unsigned short* __restrict__ Kb,
    unsigned short* __restrict__ Vt, unsigned* __restrict__ pmT)
{
    __shared__ __align__(16) short8_t ysh[16][64];
    __shared__ __align__(16) short8_t toksh[16][64];

    const int b = blockIdx.x;
    const int t = threadIdx.x;
    const int lane = t & 63;
    const int w = t >> 6;                    // wave 0..7

    if (b >= NB_EMBED) {
        // ---------------- mask-pack path ----------------
        const int sflag = *mflag;                   // uniform -> scalar load
        const int idx  = (b - NB_EMBED) * 8 + w;    // 0..9999
        const int q    = idx >> 1;                  // 0..4999
        const int half = idx & 1;                   // chunks half*10..+9

        if (sflag == 0) {
            // word mask: coalesced ballot transpose, loads hoisted for MLP
            const int* row = (const int*)mask_raw + (size_t)q * N_TOK;
            int4 u[10];
            #pragma unroll
            for (int j = 0; j < 10; ++j) {
                int wb = (half * 10 + j) * 256 + lane * 4;
                int wbc = (j == 9) ? (half ? min(wb, N_TOK - 4) : wb) : wb;
                u[j] = *(const int4*)(row + wbc);
            }
            #pragma unroll
            for (int j = 0; j < 10; ++j) {
                const int c  = half * 10 + j;
                const int wb = c * 256 + lane * 4;
                unsigned long long B0, B1, B2, B3;
                if (c < 19) {
                    B0 = __ballot(u[j].x == 0);
                    B1 = __ballot(u[j].y == 0);
                    B2 = __ballot(u[j].z == 0);
                    B3 = __ballot(u[j].w == 0);
                } else {
                    B0 = __ballot(u[j].x == 0 && wb + 0 < N_TOK);
                    B1 = __ballot(u[j].y == 0 && wb + 1 < N_TOK);
                    B2 = __ballot(u[j].z == 0 && wb + 2 < N_TOK);
                    B3 = __ballot(u[j].w == 0 && wb + 3 < N_TOK);
                }
                if (lane < 8) {
                    unsigned word =  ((unsigned)(B0 >> (8 * lane)) & 0xFFu)
                                  | (((unsigned)(B1 >> (8 * lane)) & 0xFFu) << 8)
                                  | (((unsigned)(B2 >> (8 * lane)) & 0xFFu) << 16)
                                  | (((unsigned)(B3 >> (8 * lane)) & 0xFFu) << 24);
                    pmT[(size_t)(c * 8 + lane) * QPAD + q] = word;
                }
            }
        } else {
            // byte mask fallback (defensively correct; same bit layout)
            const unsigned char* row = (const unsigned char*)mask_raw + (size_t)q * N_TOK;
            for (int kt = half * 80 + lane; kt < half * 80 + 80; kt += 64) {
                unsigned bits = 0;
                int k0 = kt * 32;
                #pragma unroll
                for (int k = 0; k < 32; ++k) {
                    int key = k0 + k;
                    if (key < N_TOK && row[key] == 0)
                        bits |= 1u << (8 * (k & 3) + (k >> 2));
                }
                pmT[(size_t)kt * QPAD + q] = bits;
            }
        }
        return;
    }

    // ---------------- embed path ----------------
    const int l31 = lane & 31, h = lane >> 5;
    const int chb = 8 * h;
    const int which = b / NKT;               // 0: Q(x)  1: K(ctx)  2: V(ctx)
    const int bx = b - which * NKT;
    const int tok0 = bx * 32;
    const int tok  = tok0 + l31;             // <= 5023 < TPAD
    const int tokc = min(tok, N_TOK - 1);    // clamp loads
    const float* img = (which == 0) ? x : ctx;
    const int hh = tokc / W_DIM, ww = tokc - hh * W_DIM;
    const float QSCALE = 0.0625f * 1.4426950408889634f;

    // cooperative y-frag build: wave w builds channel-blocks 2w, 2w+1
    #pragma unroll
    for (int i = 0; i < 2; ++i) {
        const int blk = 2 * w + i;
        float yv[8];
        #pragma unroll
        for (int j = 0; j < 8; ++j) {
            int ch = blk * 16 + chb + j;
            float pos = (ch < 128) ? col_embed[ww * 128 + ch]
                                   : row_embed[hh * 128 + (ch - 128)];
            yv[j] = img[ch * N_TOK + tokc] + pos;
        }
        union { unsigned u[4]; short8_t v; } pk;
        #pragma unroll
        for (int j = 0; j < 4; ++j) pk.u[j] = pack2bf(yv[2 * j], yv[2 * j + 1]);
        ysh[blk][lane] = pk.v;
    }
    __syncthreads();

    // GEMM1: wave w computes output channel group ct = w (16 MFMA)
    {
        f32x16 c;
        #pragma unroll
        for (int r = 0; r < 16; ++r) c[r] = 0.f;
        #pragma unroll
        for (int blk = 0; blk < 16; ++blk) {
            short8_t wf = *(const short8_t*)(Wb + (size_t)(w * 32 + l31) * 256 + blk * 16 + chb);
            c = __builtin_amdgcn_mfma_f32_32x32x16_bf16(wf, ysh[blk][lane], c, 0, 0, 0);
        }
        #pragma unroll
        for (int m = 0; m < 4; ++m) {
            float4 b4 = *(const float4*)(b_in + w * 32 + 4 * h + 8 * m);
            c[4 * m + 0] += b4.x; c[4 * m + 1] += b4.y;
            c[4 * m + 2] += b4.z; c[4 * m + 3] += b4.w;
        }
        __syncthreads();
        toksh[2 * w + 0][lane] = mkfrag(c, 0);
        toksh[2 * w + 1][lane] = mkfrag(c, 1);
    }
    __syncthreads();

    // GEMM2: wave w owns ot = w, tok-frags read from LDS just-in-time.
    const unsigned short* W2 = Wb + (which + 1) * 65536;   // wq / wk / wv
    const float* bias2 = (which == 0) ? bq : (which == 1) ? bk : bv;
    const int ot = w;
    f32x16 c;
    #pragma unroll
    for (int r = 0; r < 16; ++r) c[r] = 0.f;
    #pragma unroll
    for (int blk = 0; blk < 16; ++blk) {
        short8_t wf = *(const short8_t*)(W2 + (size_t)(ot * 32 + l31) * 256 + blk * 16 + chb);
        c = __builtin_amdgcn_mfma_f32_32x32x16_bf16(wf, toksh[blk][lane], c, 0, 0, 0);
    }
    if (which == 0) {
        #pragma unroll
        for (int m = 0; m < 4; ++m) {
            float4 b4 = *(const float4*)(bias2 + ot * 32 + 4 * h + 8 * m);
            c[4 * m + 0] = (c[4 * m + 0] + b4.x) * QSCALE;
            c[4 * m + 1] = (c[4 * m + 1] + b4.y) * QSCALE;
            c[4 * m + 2] = (c[4 * m + 2] + b4.z) * QSCALE;
            c[4 * m + 3] = (c[4 * m + 3] + b4.w) * QSCALE;
        }
    } else {
        #pragma unroll
        for (int m = 0; m < 4; ++m) {
            float4 b4 = *(const float4*)(bias2 + ot * 32 + 4 * h + 8 * m);
            c[4 * m + 0] += b4.x; c[4 * m + 1] += b4.y;
            c[4 * m + 2] += b4.z; c[4 * m + 3] += b4.w;
        }
    }
    if (which == 2) {
        // V^T tile-major: [kt=bx][head][d][k=l31]
        #pragma unroll
        for (int r = 0; r < 16; ++r) {
            int oc = ot * 32 + ((r & 3) + 8 * (r >> 2) + 4 * h);
            int hd = oc >> 5, d = oc & 31;
            Vt[((size_t)bx * 8 + hd) * 1024 + d * 32 + l31] =
                (unsigned short)f2bf(c[r]);
        }
    } else {
        unsigned short* dst = (which == 0) ? Qb : Kb;
        short8_t f0 = mkfrag(c, 0), f1 = mkfrag(c, 1);
        *(short8_t*)(dst + (size_t)ot * TPAD * 32 + (size_t)tok * 32 + chb)      = f0;
        *(short8_t*)(dst + (size_t)ot * TPAD * 32 + (size_t)tok * 32 + 16 + chb) = f1;
    }
}

// ---------------------------------------------------------------------------
// Kernel 3: MFMA flash attention, no-max softmax. Block = 8 waves = 1 qtile x
// 8 ksplits of 20 tiles each (k-space padded to 160 tiles; pads keep=0).
// Wave: 32 queries x 1 head. Swapped QK^T (S^T), O^T = V^T . P^T.
// Tile-major V^T; setprio around MFMA; sbfe keep-bit; persistent zero C-reg;
// 19-iter main loop + epilogue. head = bid&7 == XCD id -> per-XCD K/V L2 lock.
// ---------------------------------------------------------------------------
__global__ __launch_bounds__(512) void attn_mfma_kernel(
    const unsigned short* __restrict__ Qb, const unsigned short* __restrict__ Kb,
    const unsigned short* __restrict__ Vt, const unsigned* __restrict__ pmT,
    unsigned short* __restrict__ AOb)
{
    __shared__ float comb[NSPLIT - 1][17][64];

    const int t    = threadIdx.x;
    const int lane = t & 63;
    const int ks   = t >> 6;                 // 0..7
    const int bid  = blockIdx.x;
    const int head = bid & 7;
    const int q0   = (bid >> 3) * 32;
    const int l31  = lane & 31;
    const int h    = lane >> 5;
    const int grp8 = h * 8;

    const unsigned short* Kh = Kb + (size_t)head * TPAD * 32;
    const unsigned short* Qh = Qb + (size_t)head * TPAD * 32;
    const unsigned short* Vh = Vt + (size_t)head * 1024 + l31 * 32 + grp8;

    short8_t qf0 = *(const short8_t*)(Qh + (size_t)(q0 + l31) * 32 + grp8);
    short8_t qf1 = *(const short8_t*)(Qh + (size_t)(q0 + l31) * 32 + 16 + grp8);

    f32x16 oacc, zacc;
    #pragma unroll
    for (int r = 0; r < 16; ++r) { oacc[r] = 0.f; zacc[r] = 0.f; }
    float lsum = 0.f;

    const int kt0 = ks * TILES_PS;

    short8_t ka0, ka1, va0, va1; unsigned mw;
    {   // preload first tile
        int k0 = kt0 * 32;
        const unsigned short* kp = Kh + (size_t)(k0 + l31) * 32 + grp8;
        ka0 = *(const short8_t*)kp;
        ka1 = *(const short8_t*)(kp + 16);
        va0 = *(const short8_t*)(Vh + (size_t)kt0 * 8192);
        va1 = *(const short8_t*)(Vh + (size_t)kt0 * 8192 + 16);
        mw  = pmT[(size_t)kt0 * QPAD + q0 + l31];
    }

    auto compute = [&](short8_t cka0, short8_t cka1, short8_t cva0,
                       short8_t cva1, unsigned cmw) {
        // S^T = K . Q^T; Q carries scale*log2e
        f32x16 sacc;
        __builtin_amdgcn_s_setprio(1);
        sacc = __builtin_amdgcn_mfma_f32_32x32x16_bf16(cka0, qf0, zacc, 0, 0, 0);
        sacc = __builtin_amdgcn_mfma_f32_32x32x16_bf16(cka1, qf1, sacc, 0, 0, 0);
        __builtin_amdgcn_s_setprio(0);

        const unsigned mwh = cmw >> h;
        float p[16];
        #pragma unroll
        for (int r = 0; r < 16; ++r) {
            float e = __builtin_amdgcn_exp2f(sacc[r]);
            const int pos = 8 * (r & 3) + 2 * (r >> 2);
            int keep = __builtin_amdgcn_sbfe((int)mwh, pos, 1);  // 0 / -1
            p[r] = __int_as_float(__float_as_int(e) & keep);
        }
        {
            float s0 = (p[0] + p[1]) + (p[2] + p[3]);
            float s1 = (p[4] + p[5]) + (p[6] + p[7]);
            float s2 = (p[8] + p[9]) + (p[10] + p[11]);
            float s3 = (p[12] + p[13]) + (p[14] + p[15]);
            lsum += (s0 + s1) + (s2 + s3);
        }

        __builtin_amdgcn_s_setprio(1);
        #pragma unroll
        for (int c = 0; c < 2; ++c) {
            const int b = 8 * c;
            unsigned a0 = pack2bf(p[b + 0], p[b + 1]);
            unsigned b0 = pack2bf(p[b + 4], p[b + 5]);
            unsigned a1 = pack2bf(p[b + 2], p[b + 3]);
            unsigned b1 = pack2bf(p[b + 6], p[b + 7]);
            uint2v s02 = __builtin_amdgcn_permlane32_swap(a0, b0, false, false);
            uint2v s13 = __builtin_amdgcn_permlane32_swap(a1, b1, false, false);
            union { unsigned u[4]; short8_t v; } fr;
            fr.u[0] = s02.x; fr.u[1] = s13.x; fr.u[2] = s02.y; fr.u[3] = s13.y;
            oacc = __builtin_amdgcn_mfma_f32_32x32x16_bf16(c ? cva1 : cva0, fr.v, oacc, 0, 0, 0);
        }
        __builtin_amdgcn_s_setprio(0);
    };

    #pragma unroll 2
    for (int it = 0; it < TILES_PS - 1; ++it) {
        int ktn = kt0 + it + 1;
        int k0n = ktn * 32;
        const unsigned short* kpn = Kh + (size_t)(k0n + l31) * 32 + grp8;
        short8_t nka0 = *(const short8_t*)kpn;
        short8_t nka1 = *(const short8_t*)(kpn + 16);
        const unsigned short* vpn = Vh + (size_t)ktn * 8192;
        short8_t nva0 = *(const short8_t*)vpn;
        short8_t nva1 = *(const short8_t*)(vpn + 16);
        unsigned nmw  = pmT[(size_t)ktn * QPAD + q0 + l31];

        compute(ka0, ka1, va0, va1, mw);

        ka0 = nka0; ka1 = nka1; va0 = nva0; va1 = nva1; mw = nmw;
    }
    compute(ka0, ka1, va0, va1, mw);   // epilogue: last tile, no prefetch

    float lfull = lsum + __shfl_xor(lsum, 32);

    if (ks) {
        comb[ks - 1][0][lane] = lfull;
        #pragma unroll
        for (int r = 0; r < 16; ++r) comb[ks - 1][1 + r][lane] = oacc[r];
    }
    __syncthreads();
    if (ks == 0) {
        float den = lfull;
        #pragma unroll
        for (int s = 0; s < NSPLIT - 1; ++s) den += comb[s][0][lane];
        float inv = 1.f / den;
        f32x16 oc2;
        #pragma unroll
        for (int r = 0; r < 16; ++r) {
            float o = oacc[r];
            #pragma unroll
            for (int s = 0; s < NSPLIT - 1; ++s) o += comb[s][1 + r][lane];
            oc2[r] = o * inv;
        }
        short8_t f0 = mkfrag(oc2, 0), f1 = mkfrag(oc2, 1);
        int q = q0 + l31;
        if (q < N_TOK) {
            *(short8_t*)(AOb + (size_t)q * EMB_D + head * 32 + grp8)      = f0;
            *(short8_t*)(AOb + (size_t)q * EMB_D + head * 32 + 16 + grp8) = f1;
        }
    }
}

// ---------------------------------------------------------------------------
// Kernel 4: MFMA output projection. grid (157, 8): blockIdx.y = ot (32 output
// channels). 1 wave/block, 16 MFMA. C-layout == channel-major output.
// ---------------------------------------------------------------------------
__global__ __launch_bounds__(64) void proj_out_kernel(
    const unsigned short* __restrict__ AOb, const unsigned short* __restrict__ Wob,
    const float* __restrict__ b_out, float* __restrict__ out)
{
    const int lane = threadIdx.x;
    const int l31 = lane & 31, h = lane >> 5;
    const int chb = 8 * h;
    const int tok0 = blockIdx.x * 32;
    const int tok  = tok0 + l31;
    const bool vld = tok < N_TOK;
    const int ot = blockIdx.y;

    short8_t afr[16];
    #pragma unroll
    for (int blk = 0; blk < 16; ++blk)
        afr[blk] = *(const short8_t*)(AOb + (size_t)tok * EMB_D + blk * 16 + chb);

    f32x16 c;
    #pragma unroll
    for (int r = 0; r < 16; ++r) c[r] = 0.f;
    #pragma unroll
    for (int blk = 0; blk < 16; ++blk) {
        short8_t wf = *(const short8_t*)(Wob + (size_t)(ot * 32 + l31) * 256 + blk * 16 + chb);
        c = __builtin_amdgcn_mfma_f32_32x32x16_bf16(wf, afr[blk], c, 0, 0, 0);
    }
    #pragma unroll
    for (int m = 0; m < 4; ++m) {
        float4 b4 = *(const float4*)(b_out + ot * 32 + 4 * h + 8 * m);
        if (vld) {
            int row = ot * 32 + 4 * h + 8 * m;
            out[(size_t)(row + 0) * N_TOK + tok] = c[4 * m + 0] + b4.x;
            out[(size_t)(row + 1) * N_TOK + tok] = c[4 * m + 1] + b4.y;
            out[(size_t)(row + 2) * N_TOK + tok] = c[4 * m + 2] + b4.z;
            out[(size_t)(row + 3) * N_TOK + tok] = c[4 * m + 3] + b4.w;
        }
    }
}

// ---------------------------------------------------------------------------
extern "C" void kernel_launch(void* const* d_in, const int* in_sizes, int n_in,
                              void* d_out, int out_size, void* d_ws, size_t ws_size,
                              hipStream_t stream) {
    const float* x         = (const float*)d_in[0];
    const float* ctx       = (const float*)d_in[1];
    const void*  mask      = (const void*) d_in[2];
    const float* row_embed = (const float*)d_in[3];
    const float* col_embed = (const float*)d_in[4];
    const float* w_in      = (const float*)d_in[5];
    const float* b_in      = (const float*)d_in[6];
    const float* wq        = (const float*)d_in[7];
    const float* bq        = (const float*)d_in[8];
    const float* wk        = (const float*)d_in[9];
    const float* bk        = (const float*)d_in[10];
    const float* wv        = (const float*)d_in[11];
    const float* bv        = (const float*)d_in[12];
    const float* w_out     = (const float*)d_in[13];
    const float* b_out     = (const float*)d_in[14];
    float* out = (float*)d_out;

    char* ws = (char*)d_ws;
    unsigned short* Qb  = (unsigned short*)(ws);                    // 2,621,440 B
    unsigned short* Kb  = (unsigned short*)(ws + 2621440);          // 2,621,440 B
    unsigned short* Vt  = (unsigned short*)(ws + 5242880);          // 2,621,440 B
    unsigned*       pmT = (unsigned*)      (ws + 7864320);          // 3,235,840 B
    unsigned short* AOb = (unsigned short*)(ws + 11100160);         // 2,560,000 B
    unsigned short* Wb  = (unsigned short*)(ws + 13660160);         //   655,360 B
    int*          mflag = (int*)           (ws + 14315520);

    // zero the 3 V^T padding tiles (kt 157..159; tile-major -> one run)
    hipMemsetAsync(Vt + (size_t)NKT * 8 * 1024, 0,
                   (size_t)(NKT_PAD - NKT) * 8 * 1024 * 2, stream);
    wb16_kernel<<<dim3(64, 6), 256, 0, stream>>>(
        w_in, wq, wk, wv, w_out, (const unsigned*)mask, Wb, mflag);
    embed_mask_kernel<<<dim3(NB_EMBED + NB_MASK), 512, 0, stream>>>(
        x, ctx, row_embed, col_embed, Wb, b_in, bq, bk, bv, mask, mflag,
        Qb, Kb, Vt, pmT);
    attn_mfma_kernel<<<dim3(NKT * 8), 512, 0, stream>>>(Qb, Kb, Vt, pmT, AOb);
    proj_out_kernel<<<dim3(NKT, 8), 64, 0, stream>>>(AOb, Wb + 4 * 65536, b_out, out);
}